// Round 8
// baseline (137.894 us; speedup 1.0000x reference)
//
#include <hip/hip_runtime.h>
#include <hip/hip_bf16.h>

#define TT 2048
#define DDIM 1024
#define NHEAD 16
#define HD 64

typedef float f32x4 __attribute__((ext_vector_type(4)));
typedef short bf16x8 __attribute__((ext_vector_type(8)));

__device__ __forceinline__ ushort f2bf(float f) {
    __hip_bfloat16 h = __float2bfloat16(f);
    return *reinterpret_cast<ushort*>(&h);
}

// ================= pre-pass: K -> bf16 copy, V -> bf16 transpose =================
// grid (32 kv-blocks, 32 bh) x 256 thr. Writes kbf[bh][kv][d] and vt[bh][dv][kv].
__global__ __launch_bounds__(256)
void prepass_kernel(const float* __restrict__ kg, const float* __restrict__ vg,
                    ushort* __restrict__ kbf, ushort* __restrict__ vt) {
    __shared__ float vtile[64][65];
    const int tid = threadIdx.x;
    const int kv0 = (int)blockIdx.x * 64;
    const int bh  = (int)blockIdx.y;
    const int b = bh >> 4, h = bh & 15;
    const int row = tid >> 2;        // 0..63
    const int c0  = (tid & 3) * 16;  // 0,16,32,48
    const size_t gin = ((size_t)(b * TT + kv0 + row)) * DDIM + h * HD + c0;

    {   // K: convert 16 floats -> bf16, same layout (per-bh contiguous)
        ushort o[16];
        #pragma unroll
        for (int i = 0; i < 4; ++i) {
            float4 a = *(const float4*)(kg + gin + i * 4);
            o[i*4+0]=f2bf(a.x); o[i*4+1]=f2bf(a.y); o[i*4+2]=f2bf(a.z); o[i*4+3]=f2bf(a.w);
        }
        ushort* kout = kbf + ((size_t)bh * TT + kv0 + row) * HD + c0;
        *(bf16x8*)kout       = *(bf16x8*)&o[0];
        *(bf16x8*)(kout + 8) = *(bf16x8*)&o[8];
    }
    #pragma unroll
    for (int i = 0; i < 4; ++i) {   // V -> LDS (f32)
        float4 a = *(const float4*)(vg + gin + i * 4);
        vtile[row][c0 + i*4 + 0] = a.x;
        vtile[row][c0 + i*4 + 1] = a.y;
        vtile[row][c0 + i*4 + 2] = a.z;
        vtile[row][c0 + i*4 + 3] = a.w;
    }
    __syncthreads();
    {   // transposed store: dv = row, kv segment = c0
        ushort o[16];
        #pragma unroll
        for (int i = 0; i < 16; ++i) o[i] = f2bf(vtile[c0 + i][row]);
        ushort* vout = vt + ((size_t)bh * HD + row) * TT + kv0 + c0;
        *(bf16x8*)vout       = *(bf16x8*)&o[0];
        *(bf16x8*)(vout + 8) = *(bf16x8*)&o[8];
    }
}

// ================= main: 1-wave blocks, zero barriers, K/V from L2 =================
// 4096 blocks x 64 thr: 16 blocks/CU (WG cap), per-CU kv-iter total exactly 264.
__global__ __launch_bounds__(64, 2)
void attn_fast(const float* __restrict__ qg, const ushort* __restrict__ kbf,
               const ushort* __restrict__ vt, float* __restrict__ out) {
    __shared__ __align__(16) ushort lds_p[16 * 64];   // 2KB per-block P buffer (swizzled)

    const int lane = threadIdx.x;   // 0..63
    const int qr = lane & 15;
    const int hi = lane >> 4;

    // decode: xcd = flat&7 (round-robin dispatch); 4 bh per XCD (2MB bf16 K+V in L2);
    // qt direction alternates per bh-sub -> per-CU iter count uniform (264).
    const int flat = (int)blockIdx.x;      // 0..4095
    const int xcd  = flat & 7;
    const int idx  = flat >> 3;            // 0..511
    const int bs   = idx >> 7;             // 0..3
    const int r    = idx & 127;            // 0..127
    const int bh   = xcd * 4 + bs;
    const int qt   = (bs & 1) ? r : (127 - r);   // 16-row q-tiles
    const int b    = bh >> 4;
    const int h    = bh & 15;
    const int q0   = qt * 16;

    const float LOG2E  = 1.4426950408889634f;
    const float slope2 = exp2f(-0.5f * (float)(h + 1)) * LOG2E;
    const float sc2    = 0.125f * LOG2E;

    // Q fragments (B-operand of swapped QK: col=q=lane&15, k=d)
    bf16x8 qf[2];
    {
        const float* gq = qg + ((size_t)(b * TT + q0 + qr)) * DDIM + h * HD + hi * 8;
        #pragma unroll
        for (int ch = 0; ch < 2; ++ch) {
            float4 a0 = *(const float4*)(gq + ch * 32);
            float4 a1 = *(const float4*)(gq + ch * 32 + 4);
            bf16x8 w;
            w[0]=f2bf(a0.x); w[1]=f2bf(a0.y); w[2]=f2bf(a0.z); w[3]=f2bf(a0.w);
            w[4]=f2bf(a1.x); w[5]=f2bf(a1.y); w[6]=f2bf(a1.z); w[7]=f2bf(a1.w);
            qf[ch] = w;
        }
    }

    const ushort* kb = kbf + (size_t)bh * TT * HD;
    const ushort* vb = vt  + (size_t)bh * HD * TT;

    f32x4 oacc[4] = {};
    float mrun = -INFINITY, lrun = 0.f;
    const int nit = (q0 >> 6) + 1;
    const int ti  = q0 + qr;

    for (int j = 0; j < nit; ++j) {
        const int kv0  = (nit - 1 - j) * 64;      // descending from the diagonal
        const bool diag = (j == 0);
        const int stmax = diag ? ((q0 >> 4) & 3) : 3;
        const int ksmax = diag ? ((q0 >> 5) & 1) : 1;

        // ---- V fragments first: latency hides under QK + softmax ----
        bf16x8 vfr[2][4];
        #pragma unroll
        for (int ks = 0; ks < 2; ++ks)
            if (ks <= ksmax)
                #pragma unroll
                for (int dt = 0; dt < 4; ++dt)
                    vfr[ks][dt] = *(const bf16x8*)(vb + (size_t)(dt * 16 + qr) * TT + kv0 + ks * 32 + hi * 8);

        // ---- S^T = K Q^T: A=K (row=kv, 16B contiguous), B=Q ----
        f32x4 sa[4] = {};
        __builtin_amdgcn_s_setprio(1);
        #pragma unroll
        for (int st = 0; st < 4; ++st)
            if (st <= stmax) {
                const ushort* kr = kb + (size_t)(kv0 + st * 16 + qr) * HD + hi * 8;
                bf16x8 k0 = *(const bf16x8*)kr;
                bf16x8 k1 = *(const bf16x8*)(kr + 32);
                sa[st] = __builtin_amdgcn_mfma_f32_16x16x32_bf16(k0, qf[0], sa[st], 0, 0, 0);
                sa[st] = __builtin_amdgcn_mfma_f32_16x16x32_bf16(k1, qf[1], sa[st], 0, 0, 0);
            }
        __builtin_amdgcn_s_setprio(0);

        // ---- in-register online softmax (lane owns q-row qr, 16 kv values) ----
        float xv[16];
        float tm = -INFINITY;
        #pragma unroll
        for (int st = 0; st < 4; ++st)
            #pragma unroll
            for (int rr = 0; rr < 4; ++rr) {
                const int rel = kv0 + st * 16 + hi * 4 + rr - ti;
                float v = sa[st][rr] * sc2 + (float)rel * slope2;
                if (diag) v = (rel <= 0) ? v : -INFINITY;   // sa zero-init for skipped st -> masked anyway
                xv[st * 4 + rr] = v;
                tm = fmaxf(tm, v);
            }
        tm = fmaxf(tm, __shfl_xor(tm, 16));
        tm = fmaxf(tm, __shfl_xor(tm, 32));
        if (!__all(tm <= mrun + 8.f)) {   // defer-max: rare after the diagonal tile
            const float mnew = fmaxf(mrun, tm);
            const float fsc  = exp2f(mrun - mnew);
            mrun = mnew;
            lrun *= fsc;
            float fo[4];
            #pragma unroll
            for (int rr = 0; rr < 4; ++rr) fo[rr] = __shfl(fsc, hi * 4 + rr);
            #pragma unroll
            for (int dt = 0; dt < 4; ++dt)
                #pragma unroll
                for (int rr = 0; rr < 4; ++rr) oacc[dt][rr] *= fo[rr];
        }
        float psum = 0.f;
        #pragma unroll
        for (int i = 0; i < 16; ++i) { xv[i] = exp2f(xv[i] - mrun); psum += xv[i]; }
        lrun += psum;

        // ---- P -> per-block LDS (same-wave write/read, no barrier) ----
        #pragma unroll
        for (int st = 0; st < 4; ++st) {
            ushort4 w;
            w.x = f2bf(xv[st * 4 + 0]); w.y = f2bf(xv[st * 4 + 1]);
            w.z = f2bf(xv[st * 4 + 2]); w.w = f2bf(xv[st * 4 + 3]);
            const int slot8 = (st << 1) | (hi >> 1);
            *(ushort4*)&lds_p[qr * 64 + ((slot8 ^ (qr & 7)) << 3) + ((hi & 1) << 2)] = w;
        }

        // ---- O += P V : A=P (row=q), B=V^T (col=dv, 16B contiguous from global) ----
        __builtin_amdgcn_s_setprio(1);
        #pragma unroll
        for (int ks = 0; ks < 2; ++ks)
            if (ks <= ksmax) {
                bf16x8 pa = *(const bf16x8*)&lds_p[qr * 64 + ((((ks << 2) | hi) ^ (qr & 7)) << 3)];
                #pragma unroll
                for (int dt = 0; dt < 4; ++dt)
                    oacc[dt] = __builtin_amdgcn_mfma_f32_16x16x32_bf16(pa, vfr[ks][dt], oacc[dt], 0, 0, 0);
            }
        __builtin_amdgcn_s_setprio(0);
    }

    // ---- epilogue ----
    {
        float lr = lrun;
        lr += __shfl_xor(lr, 16);
        lr += __shfl_xor(lr, 32);
        const float linv = 1.0f / lr;
        #pragma unroll
        for (int rr = 0; rr < 4; ++rr) {
            const float inv = __shfl(linv, hi * 4 + rr);
            float* go = out + ((size_t)(b * TT + q0 + hi * 4 + rr)) * DDIM + h * HD;
            #pragma unroll
            for (int dt = 0; dt < 4; ++dt)
                go[dt * 16 + qr] = oacc[dt][rr] * inv;
        }
    }
}

// ================= fallback (R6 kernel, proven 76.5us) if ws too small =================
#define QBLK 64
#define KVBLK 64
#define NQT (TT / QBLK)
#define VST 72

__global__ __launch_bounds__(256, 2)
void alibi_attn_fallback(const float* __restrict__ qg,
                         const float* __restrict__ kg,
                         const float* __restrict__ vg,
                         float* __restrict__ out) {
    __shared__ __align__(16) ushort lds_k[KVBLK * HD];
    __shared__ __align__(16) ushort lds_vt[HD * VST];
    __shared__ __align__(16) ushort lds_p[4][16 * 64];

    const int tid  = threadIdx.x;
    const int wv   = tid >> 6;
    const int lane = tid & 63;
    const int hi   = lane >> 4;
    const int qr   = lane & 15;

    const int flat = (int)blockIdx.x;
    const int xcd  = flat & 7;
    const int idx  = flat >> 3;
    const int bh   = xcd * 4 + (idx >> 5);
    const int qt   = NQT - 1 - (idx & 31);
    const int b    = bh >> 4;
    const int h    = bh & 15;
    const int q0   = qt * QBLK;

    const float LOG2E  = 1.4426950408889634f;
    const float slope2 = exp2f(-0.5f * (float)(h + 1)) * LOG2E;
    const float sc2    = 0.125f * LOG2E;

    const size_t bhbase = (size_t)(b * TT) * DDIM + (size_t)(h * HD);

    bf16x8 qf[2];
    {
        const float* gq = qg + bhbase + (size_t)(q0 + wv * 16 + qr) * DDIM + hi * 8;
        #pragma unroll
        for (int ch = 0; ch < 2; ++ch) {
            float4 a0 = *(const float4*)(gq + ch * 32);
            float4 a1 = *(const float4*)(gq + ch * 32 + 4);
            bf16x8 w;
            w[0]=f2bf(a0.x); w[1]=f2bf(a0.y); w[2]=f2bf(a0.z); w[3]=f2bf(a0.w);
            w[4]=f2bf(a1.x); w[5]=f2bf(a1.y); w[6]=f2bf(a1.z); w[7]=f2bf(a1.w);
            qf[ch] = w;
        }
    }

    const int krow = tid >> 3;
    const int kcg  = tid & 7;
    const int vdv  = tid & 63;
    const int vkc  = tid >> 6;

    float ka[2][8], va[2][8];
    auto issue_loads = [&](int kv0) {
        const float* kp0 = kg + bhbase + (size_t)(kv0 + krow) * DDIM + kcg * 8;
        const float* kp1 = kp0 + (size_t)32 * DDIM;
        *(float4*)&ka[0][0] = *(const float4*)kp0; *(float4*)&ka[0][4] = *(const float4*)(kp0 + 4);
        *(float4*)&ka[1][0] = *(const float4*)kp1; *(float4*)&ka[1][4] = *(const float4*)(kp1 + 4);
        const float* vp0 = vg + bhbase + (size_t)(kv0 + vkc * 8) * DDIM + vdv;
        const float* vp1 = vp0 + (size_t)32 * DDIM;
        #pragma unroll
        for (int jj = 0; jj < 8; ++jj) {
            va[0][jj] = vp0[(size_t)jj * DDIM];
            va[1][jj] = vp1[(size_t)jj * DDIM];
        }
    };
    auto write_stage = [&]() {
        #pragma unroll
        for (int s2 = 0; s2 < 2; ++s2) {
            bf16x8 w;
            #pragma unroll
            for (int e = 0; e < 8; ++e) w[e] = f2bf(ka[s2][e]);
            const int row = krow + s2 * 32;
            *(bf16x8*)&lds_k[row * 64 + ((kcg ^ (row & 7)) << 3)] = w;
            bf16x8 u;
            #pragma unroll
            for (int e = 0; e < 8; ++e) u[e] = f2bf(va[s2][e]);
            const int kc = vkc + s2 * 4;
            *(bf16x8*)&lds_vt[vdv * VST + ((kc ^ ((vdv >> 3) & 7)) << 3)] = u;
        }
    };

    const int nit = qt + 1;
    issue_loads(q0);
    write_stage();

    f32x4 oacc[4] = {};
    float mrun = -INFINITY, lrun = 0.f;

    for (int j = 0; j < nit; ++j) {
        const int kv0 = (qt - j) * KVBLK;
        if (j + 1 < nit) issue_loads(kv0 - KVBLK);
        __syncthreads();

        const bool diag = (j == 0);

        f32x4 s_acc[4] = {};
        __builtin_amdgcn_s_setprio(1);
        #pragma unroll
        for (int st = 0; st < 4; ++st) {
            if (!diag || st <= wv) {
                const int kvrow = st * 16 + qr;
                #pragma unroll
                for (int ch = 0; ch < 2; ++ch) {
                    bf16x8 kf = *(const bf16x8*)&lds_k[kvrow * 64 + ((((ch << 2) + hi) ^ (kvrow & 7)) << 3)];
                    s_acc[st] = __builtin_amdgcn_mfma_f32_16x16x32_bf16(kf, qf[ch], s_acc[st], 0, 0, 0);
                }
            }
        }
        __builtin_amdgcn_s_setprio(0);

        const int ti = q0 + wv * 16 + qr;
        float xv[16];
        float tm = -INFINITY;
        {
            const float relb = (float)(kv0 - ti);
            #pragma unroll
            for (int st = 0; st < 4; ++st)
                #pragma unroll
                for (int rr = 0; rr < 4; ++rr) {
                    const float rel = relb + (float)(st * 16 + hi * 4 + rr);
                    float v = s_acc[st][rr] * sc2 + rel * slope2;
                    if (diag) v = (rel <= 0.f) ? v : -INFINITY;
                    xv[st * 4 + rr] = v;
                    tm = fmaxf(tm, v);
                }
        }
        tm = fmaxf(tm, __shfl_xor(tm, 16));
        tm = fmaxf(tm, __shfl_xor(tm, 32));
        if (!__all(tm <= mrun + 8.f)) {
            const float mnew = fmaxf(mrun, tm);
            const float fsc  = exp2f(mrun - mnew);
            mrun = mnew;
            lrun *= fsc;
            float fo[4];
            #pragma unroll
            for (int rr = 0; rr < 4; ++rr) fo[rr] = __shfl(fsc, hi * 4 + rr);
            #pragma unroll
            for (int dt = 0; dt < 4; ++dt)
                #pragma unroll
                for (int rr = 0; rr < 4; ++rr) oacc[dt][rr] *= fo[rr];
        }
        float psum = 0.f;
        #pragma unroll
        for (int i = 0; i < 16; ++i) { xv[i] = exp2f(xv[i] - mrun); psum += xv[i]; }
        lrun += psum;

        #pragma unroll
        for (int st = 0; st < 4; ++st) {
            ushort4 w;
            w.x = f2bf(xv[st * 4 + 0]); w.y = f2bf(xv[st * 4 + 1]);
            w.z = f2bf(xv[st * 4 + 2]); w.w = f2bf(xv[st * 4 + 3]);
            const int slot8 = (st << 1) | (hi >> 1);
            *(ushort4*)&lds_p[wv][qr * 64 + ((slot8 ^ (qr & 7)) << 3) + ((hi & 1) << 2)] = w;
        }

        __builtin_amdgcn_s_setprio(1);
        #pragma unroll
        for (int ks = 0; ks < 2; ++ks) {
            if (!diag || wv >= 2 || ks == 0) {
                bf16x8 pa = *(const bf16x8*)&lds_p[wv][qr * 64 + ((((ks << 2) | hi) ^ (qr & 7)) << 3)];
                #pragma unroll
                for (int dt = 0; dt < 4; ++dt) {
                    const int dv = dt * 16 + qr;
                    bf16x8 vbf = *(const bf16x8*)&lds_vt[dv * VST + ((((ks << 2) + hi) ^ ((dv >> 3) & 7)) << 3)];
                    oacc[dt] = __builtin_amdgcn_mfma_f32_16x16x32_bf16(pa, vbf, oacc[dt], 0, 0, 0);
                }
            }
        }
        __builtin_amdgcn_s_setprio(0);

        if (j + 1 < nit) {
            __syncthreads();
            write_stage();
        }
    }

    {
        float lr = lrun;
        lr += __shfl_xor(lr, 16);
        lr += __shfl_xor(lr, 32);
        const float linv = 1.0f / lr;
        #pragma unroll
        for (int rr = 0; rr < 4; ++rr) {
            const float inv = __shfl(linv, hi * 4 + rr);
            float* go = out + bhbase + (size_t)(q0 + wv * 16 + hi * 4 + rr) * DDIM;
            #pragma unroll
            for (int dt = 0; dt < 4; ++dt)
                go[dt * 16 + qr] = oacc[dt][rr] * inv;
        }
    }
}

extern "C" void kernel_launch(void* const* d_in, const int* in_sizes, int n_in,
                              void* d_out, int out_size, void* d_ws, size_t ws_size,
                              hipStream_t stream) {
    (void)in_sizes; (void)n_in; (void)out_size;
    const float* q = (const float*)d_in[0];
    const float* k = (const float*)d_in[1];
    const float* v = (const float*)d_in[2];
    float* o = (float*)d_out;

    const size_t elems = (size_t)2 * NHEAD * TT * HD;      // 4.19M per tensor
    const size_t need  = 2 * elems * sizeof(ushort);       // kbf + vt = 16 MB
    if (ws_size >= need) {
        ushort* kbf = (ushort*)d_ws;
        ushort* vt  = kbf + elems;
        prepass_kernel<<<dim3(32, 32), 256, 0, stream>>>(k, v, kbf, vt);
        attn_fast<<<dim3(4096), 64, 0, stream>>>(q, kbf, vt, o);
    } else {
        alibi_attn_fallback<<<dim3(1024), 256, 0, stream>>>(q, k, v, o);
    }
}

// Round 10
// 87.631 us; speedup vs baseline: 1.5736x; 1.5736x over previous
//
#include <hip/hip_runtime.h>
#include <hip/hip_bf16.h>

#define TT 2048
#define DDIM 1024
#define NHEAD 16
#define HD 64
#define QBLK 64
#define KVBLK 64
#define NQT (TT / QBLK)

typedef float f32x4 __attribute__((ext_vector_type(4)));
typedef short bf16x8 __attribute__((ext_vector_type(8)));

__device__ __forceinline__ ushort f2bf(float f) {
    __hip_bfloat16 h = __float2bfloat16(f);
    return *reinterpret_cast<ushort*>(&h);
}

// ============ pre-pass (R8-proven): K -> bf16, V -> bf16 transposed ============
// writes kbf[bh][kv][d], vt[bh][dv][kv]
__global__ __launch_bounds__(256)
void prepass_kernel(const float* __restrict__ kg, const float* __restrict__ vg,
                    ushort* __restrict__ kbf, ushort* __restrict__ vt) {
    __shared__ float vtile[64][65];
    const int tid = threadIdx.x;
    const int kv0 = (int)blockIdx.x * 64;
    const int bh  = (int)blockIdx.y;
    const int b = bh >> 4, h = bh & 15;
    const int row = tid >> 2;
    const int c0  = (tid & 3) * 16;
    const size_t gin = ((size_t)(b * TT + kv0 + row)) * DDIM + h * HD + c0;

    {
        ushort o[16];
        #pragma unroll
        for (int i = 0; i < 4; ++i) {
            float4 a = *(const float4*)(kg + gin + i * 4);
            o[i*4+0]=f2bf(a.x); o[i*4+1]=f2bf(a.y); o[i*4+2]=f2bf(a.z); o[i*4+3]=f2bf(a.w);
        }
        ushort* kout = kbf + ((size_t)bh * TT + kv0 + row) * HD + c0;
        *(bf16x8*)kout       = *(bf16x8*)&o[0];
        *(bf16x8*)(kout + 8) = *(bf16x8*)&o[8];
    }
    #pragma unroll
    for (int i = 0; i < 4; ++i) {
        float4 a = *(const float4*)(vg + gin + i * 4);
        vtile[row][c0 + i*4 + 0] = a.x;
        vtile[row][c0 + i*4 + 1] = a.y;
        vtile[row][c0 + i*4 + 2] = a.z;
        vtile[row][c0 + i*4 + 3] = a.w;
    }
    __syncthreads();
    {
        ushort o[16];
        #pragma unroll
        for (int i = 0; i < 16; ++i) o[i] = f2bf(vtile[c0 + i][row]);
        ushort* vout = vt + ((size_t)bh * HD + row) * TT + kv0 + c0;
        *(bf16x8*)vout       = *(bf16x8*)&o[0];
        *(bf16x8*)(vout + 8) = *(bf16x8*)&o[8];
    }
}

// ============ main: R6 structure + bf16 staging + double-buffer, 1 barrier/iter ============
__global__ __launch_bounds__(256, 2)
void attn_main(const float* __restrict__ qg, const ushort* __restrict__ kbf,
               const ushort* __restrict__ vt, float* __restrict__ out) {
    // dbuf K (2x8KB) + dbuf V^T (2x8KB) + per-wave P (8KB) = 40KB -> 4 blocks/CU
    __shared__ __align__(16) ushort lds_k[2][KVBLK * HD];
    __shared__ __align__(16) ushort lds_v[2][HD * KVBLK];
    __shared__ __align__(16) ushort lds_p[4][16 * 64];

    const int tid  = threadIdx.x;
    const int wv   = tid >> 6;
    const int lane = tid & 63;
    const int hi   = lane >> 4;
    const int qr   = lane & 15;

    // R6-proven decode: xcd=flat&7, 4 bh per XCD (bf16 K+V = 2MB in one L2), heavy qt first.
    const int flat = (int)blockIdx.x;          // 0..1023
    const int xcd  = flat & 7;
    const int idx  = flat >> 3;
    const int bh   = xcd * 4 + (idx >> 5);
    const int qt   = NQT - 1 - (idx & 31);
    const int b    = bh >> 4;
    const int h    = bh & 15;
    const int q0   = qt * QBLK;

    const float LOG2E  = 1.4426950408889634f;
    const float slope2 = exp2f(-0.5f * (float)(h + 1)) * LOG2E;
    const float sc2    = 0.125f * LOG2E;

    // ---- Q fragments (f32 source, once per block) ----
    bf16x8 qf[2];
    {
        const float* gq = qg + ((size_t)(b * TT + q0 + wv * 16 + qr)) * DDIM + h * HD + hi * 8;
        #pragma unroll
        for (int ch = 0; ch < 2; ++ch) {
            float4 a0 = *(const float4*)(gq + ch * 32);
            float4 a1 = *(const float4*)(gq + ch * 32 + 4);
            bf16x8 w;
            w[0]=f2bf(a0.x); w[1]=f2bf(a0.y); w[2]=f2bf(a0.z); w[3]=f2bf(a0.w);
            w[4]=f2bf(a1.x); w[5]=f2bf(a1.y); w[6]=f2bf(a1.z); w[7]=f2bf(a1.w);
            qf[ch] = w;
        }
    }

    const ushort* kb = kbf + (size_t)bh * TT * HD;
    const ushort* vb = vt  + (size_t)bh * HD * TT;

    // staging: 64 rows x 8 chunks(16B); thread -> row=tid>>2, chunks {tid&3, (tid&3)+4}
    const int srow = tid >> 2;
    const int sci  = tid & 3;

    bf16x8 kr0, kr1, vr0, vr1;
    auto stage_issue = [&](int kv0) {
        const ushort* kp = kb + (size_t)(kv0 + srow) * HD + sci * 8;
        kr0 = *(const bf16x8*)kp;
        kr1 = *(const bf16x8*)(kp + 32);
        const ushort* vp = vb + (size_t)srow * TT + kv0 + sci * 8;
        vr0 = *(const bf16x8*)vp;
        vr1 = *(const bf16x8*)(vp + 32);
    };
    auto stage_write = [&](int nb) {
        const int sw = (srow & 7);
        *(bf16x8*)&lds_k[nb][srow * 64 + ((sci ^ sw) << 3)]       = kr0;
        *(bf16x8*)&lds_k[nb][srow * 64 + (((sci + 4) ^ sw) << 3)] = kr1;
        *(bf16x8*)&lds_v[nb][srow * 64 + ((sci ^ sw) << 3)]       = vr0;
        *(bf16x8*)&lds_v[nb][srow * 64 + (((sci + 4) ^ sw) << 3)] = vr1;
    };

    const int nit = qt + 1;
    stage_issue(q0);
    stage_write(0);

    f32x4 oacc[4] = {};
    float mrun = -INFINITY, lrun = 0.f;
    const int ti = q0 + wv * 16 + qr;

    for (int j = 0; j < nit; ++j) {
        const int buf = j & 1;
        const int kv0 = q0 - j * KVBLK;                      // descending
        if (j + 1 < nit) stage_issue(kv0 - KVBLK);           // in flight across compute
        __syncthreads();   // buf writes visible; prior reads of buf^1 complete

        const bool diag = (j == 0);

        // ---- S^T = K Q^T ----
        f32x4 sa[4] = {};
        __builtin_amdgcn_s_setprio(1);
        #pragma unroll
        for (int st = 0; st < 4; ++st) {
            if (!diag || st <= wv) {
                const int krow = st * 16 + qr;
                const int sw = (krow & 7);
                bf16x8 k0 = *(const bf16x8*)&lds_k[buf][krow * 64 + ((hi ^ sw) << 3)];
                bf16x8 k1 = *(const bf16x8*)&lds_k[buf][krow * 64 + (((4 + hi) ^ sw) << 3)];
                sa[st] = __builtin_amdgcn_mfma_f32_16x16x32_bf16(k0, qf[0], sa[st], 0, 0, 0);
                sa[st] = __builtin_amdgcn_mfma_f32_16x16x32_bf16(k1, qf[1], sa[st], 0, 0, 0);
            }
        }
        __builtin_amdgcn_s_setprio(0);

        // ---- in-register online softmax (lane owns q-row qr, 16 kv values) ----
        // EXACT integer-domain rel (R6-proven): rel = kv0 - ti + hi*4 + st*16 + rr.
        // R9 bug: masking on fmaf(a,slope2,vbase) <= 0 — two roundings make the
        // diagonal's exact-0 land at ~±a*slope2*2^-24; positive -> top logit masked.
        const float relb = (float)(kv0 - ti + hi * 4);
        float xv[16];
        float tm = -INFINITY;
        #pragma unroll
        for (int st = 0; st < 4; ++st)
            #pragma unroll
            for (int rr = 0; rr < 4; ++rr) {
                const float rel = relb + (float)(st * 16 + rr);   // exact small-int float
                float v = fmaf(sa[st][rr], sc2, rel * slope2);
                if (diag) v = (rel <= 0.f) ? v : -INFINITY;
                xv[st * 4 + rr] = v;
                tm = fmaxf(tm, v);
            }
        tm = fmaxf(tm, __shfl_xor(tm, 16));
        tm = fmaxf(tm, __shfl_xor(tm, 32));
        if (!__all(tm <= mrun + 8.f)) {   // defer-max: rare after the diagonal tile
            const float mnew = fmaxf(mrun, tm);
            const float fsc  = exp2f(mrun - mnew);
            mrun = mnew;
            lrun *= fsc;
            float fo[4];
            #pragma unroll
            for (int rr = 0; rr < 4; ++rr) fo[rr] = __shfl(fsc, hi * 4 + rr);
            #pragma unroll
            for (int dt = 0; dt < 4; ++dt)
                #pragma unroll
                for (int rr = 0; rr < 4; ++rr) oacc[dt][rr] *= fo[rr];
        }
        float psum = 0.f;
        #pragma unroll
        for (int i = 0; i < 16; ++i) { xv[i] = exp2f(xv[i] - mrun); psum += xv[i]; }
        lrun += psum;

        // ---- P -> per-wave LDS (swizzled; same-wave producer/consumer, no barrier) ----
        #pragma unroll
        for (int st = 0; st < 4; ++st) {
            ushort4 w;
            w.x = f2bf(xv[st * 4 + 0]); w.y = f2bf(xv[st * 4 + 1]);
            w.z = f2bf(xv[st * 4 + 2]); w.w = f2bf(xv[st * 4 + 3]);
            const int slot8 = (st << 1) | (hi >> 1);
            *(ushort4*)&lds_p[wv][qr * 64 + ((slot8 ^ (qr & 7)) << 3) + ((hi & 1) << 2)] = w;
        }

        // ---- O += P V ----
        __builtin_amdgcn_s_setprio(1);
        #pragma unroll
        for (int ks = 0; ks < 2; ++ks) {
            if (!diag || wv >= 2 || ks == 0) {
                bf16x8 pa = *(const bf16x8*)&lds_p[wv][qr * 64 + ((((ks << 2) | hi) ^ (qr & 7)) << 3)];
                #pragma unroll
                for (int dt = 0; dt < 4; ++dt) {
                    const int dv = dt * 16 + qr;
                    bf16x8 vbf = *(const bf16x8*)&lds_v[buf][dv * 64 + ((((ks << 2) + hi) ^ (dv & 7)) << 3)];
                    oacc[dt] = __builtin_amdgcn_mfma_f32_16x16x32_bf16(pa, vbf, oacc[dt], 0, 0, 0);
                }
            }
        }
        __builtin_amdgcn_s_setprio(0);

        if (j + 1 < nit) stage_write(buf ^ 1);   // next tile; nobody reads buf^1 this iter
    }

    // ---- epilogue ----
    {
        float lr = lrun;
        lr += __shfl_xor(lr, 16);
        lr += __shfl_xor(lr, 32);
        const float linv = 1.0f / lr;
        #pragma unroll
        for (int rr = 0; rr < 4; ++rr) {
            const float inv = __shfl(linv, hi * 4 + rr);
            float* go = out + ((size_t)(b * TT + q0 + wv * 16 + hi * 4 + rr)) * DDIM + h * HD;
            #pragma unroll
            for (int dt = 0; dt < 4; ++dt)
                go[dt * 16 + qr] = oacc[dt][rr] * inv;
        }
    }
}

// ============ fallback (R6 kernel, proven 76.5us) if ws too small ============
#define VST 72
__global__ __launch_bounds__(256, 2)
void alibi_attn_fallback(const float* __restrict__ qg,
                         const float* __restrict__ kg,
                         const float* __restrict__ vg,
                         float* __restrict__ out) {
    __shared__ __align__(16) ushort lds_k[KVBLK * HD];
    __shared__ __align__(16) ushort lds_vt[HD * VST];
    __shared__ __align__(16) ushort lds_p[4][16 * 64];

    const int tid  = threadIdx.x;
    const int wv   = tid >> 6;
    const int lane = tid & 63;
    const int hi   = lane >> 4;
    const int qr   = lane & 15;

    const int flat = (int)blockIdx.x;
    const int xcd  = flat & 7;
    const int idx  = flat >> 3;
    const int bh   = xcd * 4 + (idx >> 5);
    const int qt   = NQT - 1 - (idx & 31);
    const int b    = bh >> 4;
    const int h    = bh & 15;
    const int q0   = qt * QBLK;

    const float LOG2E  = 1.4426950408889634f;
    const float slope2 = exp2f(-0.5f * (float)(h + 1)) * LOG2E;
    const float sc2    = 0.125f * LOG2E;

    const size_t bhbase = (size_t)(b * TT) * DDIM + (size_t)(h * HD);

    bf16x8 qf[2];
    {
        const float* gq = qg + bhbase + (size_t)(q0 + wv * 16 + qr) * DDIM + hi * 8;
        #pragma unroll
        for (int ch = 0; ch < 2; ++ch) {
            float4 a0 = *(const float4*)(gq + ch * 32);
            float4 a1 = *(const float4*)(gq + ch * 32 + 4);
            bf16x8 w;
            w[0]=f2bf(a0.x); w[1]=f2bf(a0.y); w[2]=f2bf(a0.z); w[3]=f2bf(a0.w);
            w[4]=f2bf(a1.x); w[5]=f2bf(a1.y); w[6]=f2bf(a1.z); w[7]=f2bf(a1.w);
            qf[ch] = w;
        }
    }

    const int krow = tid >> 3;
    const int kcg  = tid & 7;
    const int vdv  = tid & 63;
    const int vkc  = tid >> 6;

    float ka[2][8], va[2][8];
    auto issue_loads = [&](int kv0) {
        const float* kp0 = kg + bhbase + (size_t)(kv0 + krow) * DDIM + kcg * 8;
        const float* kp1 = kp0 + (size_t)32 * DDIM;
        *(float4*)&ka[0][0] = *(const float4*)kp0; *(float4*)&ka[0][4] = *(const float4*)(kp0 + 4);
        *(float4*)&ka[1][0] = *(const float4*)kp1; *(float4*)&ka[1][4] = *(const float4*)(kp1 + 4);
        const float* vp0 = vg + bhbase + (size_t)(kv0 + vkc * 8) * DDIM + vdv;
        const float* vp1 = vp0 + (size_t)32 * DDIM;
        #pragma unroll
        for (int jj = 0; jj < 8; ++jj) {
            va[0][jj] = vp0[(size_t)jj * DDIM];
            va[1][jj] = vp1[(size_t)jj * DDIM];
        }
    };
    auto write_stage = [&]() {
        #pragma unroll
        for (int s2 = 0; s2 < 2; ++s2) {
            bf16x8 w;
            #pragma unroll
            for (int e = 0; e < 8; ++e) w[e] = f2bf(ka[s2][e]);
            const int row = krow + s2 * 32;
            *(bf16x8*)&lds_k[row * 64 + ((kcg ^ (row & 7)) << 3)] = w;
            bf16x8 u;
            #pragma unroll
            for (int e = 0; e < 8; ++e) u[e] = f2bf(va[s2][e]);
            const int kc = vkc + s2 * 4;
            *(bf16x8*)&lds_vt[vdv * VST + ((kc ^ ((vdv >> 3) & 7)) << 3)] = u;
        }
    };

    const int nit = qt + 1;
    issue_loads(q0);
    write_stage();

    f32x4 oacc[4] = {};
    float mrun = -INFINITY, lrun = 0.f;

    for (int j = 0; j < nit; ++j) {
        const int kv0 = (qt - j) * KVBLK;
        if (j + 1 < nit) issue_loads(kv0 - KVBLK);
        __syncthreads();

        const bool diag = (j == 0);

        f32x4 s_acc[4] = {};
        __builtin_amdgcn_s_setprio(1);
        #pragma unroll
        for (int st = 0; st < 4; ++st) {
            if (!diag || st <= wv) {
                const int kvrow = st * 16 + qr;
                #pragma unroll
                for (int ch = 0; ch < 2; ++ch) {
                    bf16x8 kf = *(const bf16x8*)&lds_k[kvrow * 64 + ((((ch << 2) + hi) ^ (kvrow & 7)) << 3)];
                    s_acc[st] = __builtin_amdgcn_mfma_f32_16x16x32_bf16(kf, qf[ch], s_acc[st], 0, 0, 0);
                }
            }
        }
        __builtin_amdgcn_s_setprio(0);

        const int ti = q0 + wv * 16 + qr;
        float xv[16];
        float tm = -INFINITY;
        {
            const float relb = (float)(kv0 - ti);
            #pragma unroll
            for (int st = 0; st < 4; ++st)
                #pragma unroll
                for (int rr = 0; rr < 4; ++rr) {
                    const float rel = relb + (float)(st * 16 + hi * 4 + rr);
                    float v = s_acc[st][rr] * sc2 + rel * slope2;
                    if (diag) v = (rel <= 0.f) ? v : -INFINITY;
                    xv[st * 4 + rr] = v;
                    tm = fmaxf(tm, v);
                }
        }
        tm = fmaxf(tm, __shfl_xor(tm, 16));
        tm = fmaxf(tm, __shfl_xor(tm, 32));
        if (!__all(tm <= mrun + 8.f)) {
            const float mnew = fmaxf(mrun, tm);
            const float fsc  = exp2f(mrun - mnew);
            mrun = mnew;
            lrun *= fsc;
            float fo[4];
            #pragma unroll
            for (int rr = 0; rr < 4; ++rr) fo[rr] = __shfl(fsc, hi * 4 + rr);
            #pragma unroll
            for (int dt = 0; dt < 4; ++dt)
                #pragma unroll
                for (int rr = 0; rr < 4; ++rr) oacc[dt][rr] *= fo[rr];
        }
        float psum = 0.f;
        #pragma unroll
        for (int i = 0; i < 16; ++i) { xv[i] = exp2f(xv[i] - mrun); psum += xv[i]; }
        lrun += psum;

        #pragma unroll
        for (int st = 0; st < 4; ++st) {
            ushort4 w;
            w.x = f2bf(xv[st * 4 + 0]); w.y = f2bf(xv[st * 4 + 1]);
            w.z = f2bf(xv[st * 4 + 2]); w.w = f2bf(xv[st * 4 + 3]);
            const int slot8 = (st << 1) | (hi >> 1);
            *(ushort4*)&lds_p[wv][qr * 64 + ((slot8 ^ (qr & 7)) << 3) + ((hi & 1) << 2)] = w;
        }

        __builtin_amdgcn_s_setprio(1);
        #pragma unroll
        for (int ks = 0; ks < 2; ++ks) {
            if (!diag || wv >= 2 || ks == 0) {
                bf16x8 pa = *(const bf16x8*)&lds_p[wv][qr * 64 + ((((ks << 2) | hi) ^ (qr & 7)) << 3)];
                #pragma unroll
                for (int dt = 0; dt < 4; ++dt) {
                    const int dv = dt * 16 + qr;
                    bf16x8 vbf = *(const bf16x8*)&lds_vt[dv * VST + ((((ks << 2) + hi) ^ ((dv >> 3) & 7)) << 3)];
                    oacc[dt] = __builtin_amdgcn_mfma_f32_16x16x32_bf16(pa, vbf, oacc[dt], 0, 0, 0);
                }
            }
        }
        __builtin_amdgcn_s_setprio(0);

        if (j + 1 < nit) {
            __syncthreads();
            write_stage();
        }
    }

    {
        float lr = lrun;
        lr += __shfl_xor(lr, 16);
        lr += __shfl_xor(lr, 32);
        const float linv = 1.0f / lr;
        #pragma unroll
        for (int rr = 0; rr < 4; ++rr) {
            const float inv = __shfl(linv, hi * 4 + rr);
            float* go = out + bhbase + (size_t)(q0 + wv * 16 + hi * 4 + rr) * DDIM;
            #pragma unroll
            for (int dt = 0; dt < 4; ++dt)
                go[dt * 16 + qr] = oacc[dt][rr] * inv;
        }
    }
}

extern "C" void kernel_launch(void* const* d_in, const int* in_sizes, int n_in,
                              void* d_out, int out_size, void* d_ws, size_t ws_size,
                              hipStream_t stream) {
    (void)in_sizes; (void)n_in; (void)out_size;
    const float* q = (const float*)d_in[0];
    const float* k = (const float*)d_in[1];
    const float* v = (const float*)d_in[2];
    float* o = (float*)d_out;

    const size_t elems = (size_t)2 * NHEAD * TT * HD;
    const size_t need  = 2 * elems * sizeof(ushort);       // 16 MB
    if (ws_size >= need) {
        ushort* kbf = (ushort*)d_ws;
        ushort* vt  = kbf + elems;
        prepass_kernel<<<dim3(32, 32), 256, 0, stream>>>(k, v, kbf, vt);
        attn_main<<<dim3(1024), 256, 0, stream>>>(q, kbf, vt, o);
    } else {
        alibi_attn_fallback<<<dim3(1024), 256, 0, stream>>>(q, k, v, o);
    }
}

// Round 11
// 65.340 us; speedup vs baseline: 2.1104x; 1.3411x over previous
//
#include <hip/hip_runtime.h>
#include <hip/hip_bf16.h>

#define TT 2048
#define DDIM 1024
#define NHEAD 16
#define HD 64
#define QBLK 64
#define KVBLK 64
#define NQT (TT / QBLK)

typedef float f32x4 __attribute__((ext_vector_type(4)));
typedef short bf16x8 __attribute__((ext_vector_type(8)));

__device__ __forceinline__ ushort f2bf(float f) {
    __hip_bfloat16 h = __float2bfloat16(f);
    return *reinterpret_cast<ushort*>(&h);
}

// barrier WITHOUT the compiler's vmcnt(0) drain: LDS writes must be visible
// (lgkmcnt 0), but prefetch global loads stay in flight across the barrier.
// (hipcc's __syncthreads emits s_waitcnt vmcnt(0) lgkmcnt(0) — that drain was
//  serializing every iteration; m194-m201-verified pattern.)
__device__ __forceinline__ void barrier_lgkm_only() {
    asm volatile("s_waitcnt lgkmcnt(0)" ::: "memory");
    __builtin_amdgcn_s_barrier();
}

// ============ pre-pass (R8-proven): K -> bf16, V -> bf16 transposed ============
__global__ __launch_bounds__(256)
void prepass_kernel(const float* __restrict__ kg, const float* __restrict__ vg,
                    ushort* __restrict__ kbf, ushort* __restrict__ vt) {
    __shared__ float vtile[64][65];
    const int tid = threadIdx.x;
    const int kv0 = (int)blockIdx.x * 64;
    const int bh  = (int)blockIdx.y;
    const int b = bh >> 4, h = bh & 15;
    const int row = tid >> 2;
    const int c0  = (tid & 3) * 16;
    const size_t gin = ((size_t)(b * TT + kv0 + row)) * DDIM + h * HD + c0;

    {
        ushort o[16];
        #pragma unroll
        for (int i = 0; i < 4; ++i) {
            float4 a = *(const float4*)(kg + gin + i * 4);
            o[i*4+0]=f2bf(a.x); o[i*4+1]=f2bf(a.y); o[i*4+2]=f2bf(a.z); o[i*4+3]=f2bf(a.w);
        }
        ushort* kout = kbf + ((size_t)bh * TT + kv0 + row) * HD + c0;
        *(bf16x8*)kout       = *(bf16x8*)&o[0];
        *(bf16x8*)(kout + 8) = *(bf16x8*)&o[8];
    }
    #pragma unroll
    for (int i = 0; i < 4; ++i) {
        float4 a = *(const float4*)(vg + gin + i * 4);
        vtile[row][c0 + i*4 + 0] = a.x;
        vtile[row][c0 + i*4 + 1] = a.y;
        vtile[row][c0 + i*4 + 2] = a.z;
        vtile[row][c0 + i*4 + 3] = a.w;
    }
    __syncthreads();
    {
        ushort o[16];
        #pragma unroll
        for (int i = 0; i < 16; ++i) o[i] = f2bf(vtile[c0 + i][row]);
        ushort* vout = vt + ((size_t)bh * HD + row) * TT + kv0 + c0;
        *(bf16x8*)vout       = *(bf16x8*)&o[0];
        *(bf16x8*)(vout + 8) = *(bf16x8*)&o[8];
    }
}

// ============ main: bf16 staging + dbuf + counted-wait barrier (T4) ============
__global__ __launch_bounds__(256, 2)
void attn_main(const float* __restrict__ qg, const ushort* __restrict__ kbf,
               const ushort* __restrict__ vt, float* __restrict__ out) {
    __shared__ __align__(16) ushort lds_k[2][KVBLK * HD];
    __shared__ __align__(16) ushort lds_v[2][HD * KVBLK];
    __shared__ __align__(16) ushort lds_p[4][16 * 64];

    const int tid  = threadIdx.x;
    const int wv   = tid >> 6;
    const int lane = tid & 63;
    const int hi   = lane >> 4;
    const int qr   = lane & 15;

    // XCD decode (R6-proven: FETCH 195->16-26MB) + R7 balanced qt map: CU slot s
    // gets qt {31-s, s, 31-s, s} -> 66 kv-iters on every CU (matters now that the
    // barrier drain is gone and heavy CUs become throughput-bound).
    const int flat = (int)blockIdx.x;          // 0..1023
    const int xcd  = flat & 7;
    const int idx  = flat >> 3;
    const int bs   = idx >> 5;                 // 0..3
    const int s    = idx & 31;
    const int bh   = xcd * 4 + bs;
    const int qt   = (bs & 1) ? s : (NQT - 1 - s);
    const int b    = bh >> 4;
    const int h    = bh & 15;
    const int q0   = qt * QBLK;

    const float LOG2E  = 1.4426950408889634f;
    const float slope2 = exp2f(-0.5f * (float)(h + 1)) * LOG2E;
    const float sc2    = 0.125f * LOG2E;

    // ---- Q fragments ----
    bf16x8 qf[2];
    {
        const float* gq = qg + ((size_t)(b * TT + q0 + wv * 16 + qr)) * DDIM + h * HD + hi * 8;
        #pragma unroll
        for (int ch = 0; ch < 2; ++ch) {
            float4 a0 = *(const float4*)(gq + ch * 32);
            float4 a1 = *(const float4*)(gq + ch * 32 + 4);
            bf16x8 w;
            w[0]=f2bf(a0.x); w[1]=f2bf(a0.y); w[2]=f2bf(a0.z); w[3]=f2bf(a0.w);
            w[4]=f2bf(a1.x); w[5]=f2bf(a1.y); w[6]=f2bf(a1.z); w[7]=f2bf(a1.w);
            qf[ch] = w;
        }
    }

    const ushort* kb = kbf + (size_t)bh * TT * HD;
    const ushort* vb = vt  + (size_t)bh * HD * TT;

    const int srow = tid >> 2;
    const int sci  = tid & 3;

    bf16x8 kr0, kr1, vr0, vr1;
    auto stage_issue = [&](int kv0) {
        const ushort* kp = kb + (size_t)(kv0 + srow) * HD + sci * 8;
        kr0 = *(const bf16x8*)kp;
        kr1 = *(const bf16x8*)(kp + 32);
        const ushort* vp = vb + (size_t)srow * TT + kv0 + sci * 8;
        vr0 = *(const bf16x8*)vp;
        vr1 = *(const bf16x8*)(vp + 32);
    };
    auto stage_write = [&](int nb) {
        const int sw = (srow & 7);
        *(bf16x8*)&lds_k[nb][srow * 64 + ((sci ^ sw) << 3)]       = kr0;
        *(bf16x8*)&lds_k[nb][srow * 64 + (((sci + 4) ^ sw) << 3)] = kr1;
        *(bf16x8*)&lds_v[nb][srow * 64 + ((sci ^ sw) << 3)]       = vr0;
        *(bf16x8*)&lds_v[nb][srow * 64 + (((sci + 4) ^ sw) << 3)] = vr1;
    };

    const int nit = qt + 1;
    stage_issue(q0);
    stage_write(0);

    f32x4 oacc[4] = {};
    float mrun = -INFINITY, lrun = 0.f;
    const int ti = q0 + wv * 16 + qr;

    for (int j = 0; j < nit; ++j) {
        const int buf = j & 1;
        const int kv0 = q0 - j * KVBLK;
        if (j + 1 < nit) stage_issue(kv0 - KVBLK);   // loads stay in flight ACROSS the barrier
        barrier_lgkm_only();                          // LDS-visibility only; no vmcnt drain

        const bool diag = (j == 0);

        // ---- S^T = K Q^T ----
        f32x4 sa[4] = {};
        __builtin_amdgcn_s_setprio(1);
        #pragma unroll
        for (int st = 0; st < 4; ++st) {
            if (!diag || st <= wv) {
                const int krow = st * 16 + qr;
                const int sw = (krow & 7);
                bf16x8 k0 = *(const bf16x8*)&lds_k[buf][krow * 64 + ((hi ^ sw) << 3)];
                bf16x8 k1 = *(const bf16x8*)&lds_k[buf][krow * 64 + (((4 + hi) ^ sw) << 3)];
                sa[st] = __builtin_amdgcn_mfma_f32_16x16x32_bf16(k0, qf[0], sa[st], 0, 0, 0);
                sa[st] = __builtin_amdgcn_mfma_f32_16x16x32_bf16(k1, qf[1], sa[st], 0, 0, 0);
            }
        }
        __builtin_amdgcn_s_setprio(0);

        // ---- in-register online softmax (exact integer-domain rel; R9 lesson) ----
        const float relb = (float)(kv0 - ti + hi * 4);
        float xv[16];
        float tm = -INFINITY;
        #pragma unroll
        for (int st = 0; st < 4; ++st)
            #pragma unroll
            for (int rr = 0; rr < 4; ++rr) {
                const float rel = relb + (float)(st * 16 + rr);
                float v = fmaf(sa[st][rr], sc2, rel * slope2);
                if (diag) v = (rel <= 0.f) ? v : -INFINITY;
                xv[st * 4 + rr] = v;
                tm = fmaxf(tm, v);
            }
        tm = fmaxf(tm, __shfl_xor(tm, 16));
        tm = fmaxf(tm, __shfl_xor(tm, 32));
        if (!__all(tm <= mrun + 8.f)) {
            const float mnew = fmaxf(mrun, tm);
            const float fsc  = exp2f(mrun - mnew);
            mrun = mnew;
            lrun *= fsc;
            float fo[4];
            #pragma unroll
            for (int rr = 0; rr < 4; ++rr) fo[rr] = __shfl(fsc, hi * 4 + rr);
            #pragma unroll
            for (int dt = 0; dt < 4; ++dt)
                #pragma unroll
                for (int rr = 0; rr < 4; ++rr) oacc[dt][rr] *= fo[rr];
        }
        float psum = 0.f;
        #pragma unroll
        for (int i = 0; i < 16; ++i) { xv[i] = exp2f(xv[i] - mrun); psum += xv[i]; }
        lrun += psum;

        // ---- P -> per-wave LDS (same-wave producer/consumer) ----
        #pragma unroll
        for (int st = 0; st < 4; ++st) {
            ushort4 w;
            w.x = f2bf(xv[st * 4 + 0]); w.y = f2bf(xv[st * 4 + 1]);
            w.z = f2bf(xv[st * 4 + 2]); w.w = f2bf(xv[st * 4 + 3]);
            const int slot8 = (st << 1) | (hi >> 1);
            *(ushort4*)&lds_p[wv][qr * 64 + ((slot8 ^ (qr & 7)) << 3) + ((hi & 1) << 2)] = w;
        }

        // ---- O += P V ----
        __builtin_amdgcn_s_setprio(1);
        #pragma unroll
        for (int ks = 0; ks < 2; ++ks) {
            if (!diag || wv >= 2 || ks == 0) {
                bf16x8 pa = *(const bf16x8*)&lds_p[wv][qr * 64 + ((((ks << 2) | hi) ^ (qr & 7)) << 3)];
                #pragma unroll
                for (int dt = 0; dt < 4; ++dt) {
                    const int dv = dt * 16 + qr;
                    bf16x8 vbf = *(const bf16x8*)&lds_v[buf][dv * 64 + ((((ks << 2) + hi) ^ (dv & 7)) << 3)];
                    oacc[dt] = __builtin_amdgcn_mfma_f32_16x16x32_bf16(pa, vbf, oacc[dt], 0, 0, 0);
                }
            }
        }
        __builtin_amdgcn_s_setprio(0);

        if (j + 1 < nit) stage_write(buf ^ 1);   // vmcnt wait lands HERE (compiler-inserted)
    }

    // ---- epilogue ----
    {
        float lr = lrun;
        lr += __shfl_xor(lr, 16);
        lr += __shfl_xor(lr, 32);
        const float linv = 1.0f / lr;
        #pragma unroll
        for (int rr = 0; rr < 4; ++rr) {
            const float inv = __shfl(linv, hi * 4 + rr);
            float* go = out + ((size_t)(b * TT + q0 + wv * 16 + hi * 4 + rr)) * DDIM + h * HD;
            #pragma unroll
            for (int dt = 0; dt < 4; ++dt)
                go[dt * 16 + qr] = oacc[dt][rr] * inv;
        }
    }
}

// ============ fallback (R6 kernel, proven 76.5us) if ws too small ============
#define VST 72
__global__ __launch_bounds__(256, 2)
void alibi_attn_fallback(const float* __restrict__ qg,
                         const float* __restrict__ kg,
                         const float* __restrict__ vg,
                         float* __restrict__ out) {
    __shared__ __align__(16) ushort lds_k[KVBLK * HD];
    __shared__ __align__(16) ushort lds_vt[HD * VST];
    __shared__ __align__(16) ushort lds_p[4][16 * 64];

    const int tid  = threadIdx.x;
    const int wv   = tid >> 6;
    const int lane = tid & 63;
    const int hi   = lane >> 4;
    const int qr   = lane & 15;

    const int flat = (int)blockIdx.x;
    const int xcd  = flat & 7;
    const int idx  = flat >> 3;
    const int bh   = xcd * 4 + (idx >> 5);
    const int qt   = NQT - 1 - (idx & 31);
    const int b    = bh >> 4;
    const int h    = bh & 15;
    const int q0   = qt * QBLK;

    const float LOG2E  = 1.4426950408889634f;
    const float slope2 = exp2f(-0.5f * (float)(h + 1)) * LOG2E;
    const float sc2    = 0.125f * LOG2E;

    const size_t bhbase = (size_t)(b * TT) * DDIM + (size_t)(h * HD);

    bf16x8 qf[2];
    {
        const float* gq = qg + bhbase + (size_t)(q0 + wv * 16 + qr) * DDIM + hi * 8;
        #pragma unroll
        for (int ch = 0; ch < 2; ++ch) {
            float4 a0 = *(const float4*)(gq + ch * 32);
            float4 a1 = *(const float4*)(gq + ch * 32 + 4);
            bf16x8 w;
            w[0]=f2bf(a0.x); w[1]=f2bf(a0.y); w[2]=f2bf(a0.z); w[3]=f2bf(a0.w);
            w[4]=f2bf(a1.x); w[5]=f2bf(a1.y); w[6]=f2bf(a1.z); w[7]=f2bf(a1.w);
            qf[ch] = w;
        }
    }

    const int krow = tid >> 3;
    const int kcg  = tid & 7;
    const int vdv  = tid & 63;
    const int vkc  = tid >> 6;

    float ka[2][8], va[2][8];
    auto issue_loads = [&](int kv0) {
        const float* kp0 = kg + bhbase + (size_t)(kv0 + krow) * DDIM + kcg * 8;
        const float* kp1 = kp0 + (size_t)32 * DDIM;
        *(float4*)&ka[0][0] = *(const float4*)kp0; *(float4*)&ka[0][4] = *(const float4*)(kp0 + 4);
        *(float4*)&ka[1][0] = *(const float4*)kp1; *(float4*)&ka[1][4] = *(const float4*)(kp1 + 4);
        const float* vp0 = vg + bhbase + (size_t)(kv0 + vkc * 8) * DDIM + vdv;
        const float* vp1 = vp0 + (size_t)32 * DDIM;
        #pragma unroll
        for (int jj = 0; jj < 8; ++jj) {
            va[0][jj] = vp0[(size_t)jj * DDIM];
            va[1][jj] = vp1[(size_t)jj * DDIM];
        }
    };
    auto write_stage = [&]() {
        #pragma unroll
        for (int s2 = 0; s2 < 2; ++s2) {
            bf16x8 w;
            #pragma unroll
            for (int e = 0; e < 8; ++e) w[e] = f2bf(ka[s2][e]);
            const int row = krow + s2 * 32;
            *(bf16x8*)&lds_k[row * 64 + ((kcg ^ (row & 7)) << 3)] = w;
            bf16x8 u;
            #pragma unroll
            for (int e = 0; e < 8; ++e) u[e] = f2bf(va[s2][e]);
            const int kc = vkc + s2 * 4;
            *(bf16x8*)&lds_vt[vdv * VST + ((kc ^ ((vdv >> 3) & 7)) << 3)] = u;
        }
    };

    const int nit = qt + 1;
    issue_loads(q0);
    write_stage();

    f32x4 oacc[4] = {};
    float mrun = -INFINITY, lrun = 0.f;

    for (int j = 0; j < nit; ++j) {
        const int kv0 = (qt - j) * KVBLK;
        if (j + 1 < nit) issue_loads(kv0 - KVBLK);
        __syncthreads();

        const bool diag = (j == 0);

        f32x4 s_acc[4] = {};
        __builtin_amdgcn_s_setprio(1);
        #pragma unroll
        for (int st = 0; st < 4; ++st) {
            if (!diag || st <= wv) {
                const int kvrow = st * 16 + qr;
                #pragma unroll
                for (int ch = 0; ch < 2; ++ch) {
                    bf16x8 kf = *(const bf16x8*)&lds_k[kvrow * 64 + ((((ch << 2) + hi) ^ (kvrow & 7)) << 3)];
                    s_acc[st] = __builtin_amdgcn_mfma_f32_16x16x32_bf16(kf, qf[ch], s_acc[st], 0, 0, 0);
                }
            }
        }
        __builtin_amdgcn_s_setprio(0);

        const int ti = q0 + wv * 16 + qr;
        float xv[16];
        float tm = -INFINITY;
        {
            const float relb = (float)(kv0 - ti);
            #pragma unroll
            for (int st = 0; st < 4; ++st)
                #pragma unroll
                for (int rr = 0; rr < 4; ++rr) {
                    const float rel = relb + (float)(st * 16 + hi * 4 + rr);
                    float v = s_acc[st][rr] * sc2 + rel * slope2;
                    if (diag) v = (rel <= 0.f) ? v : -INFINITY;
                    xv[st * 4 + rr] = v;
                    tm = fmaxf(tm, v);
                }
        }
        tm = fmaxf(tm, __shfl_xor(tm, 16));
        tm = fmaxf(tm, __shfl_xor(tm, 32));
        if (!__all(tm <= mrun + 8.f)) {
            const float mnew = fmaxf(mrun, tm);
            const float fsc  = exp2f(mrun - mnew);
            mrun = mnew;
            lrun *= fsc;
            float fo[4];
            #pragma unroll
            for (int rr = 0; rr < 4; ++rr) fo[rr] = __shfl(fsc, hi * 4 + rr);
            #pragma unroll
            for (int dt = 0; dt < 4; ++dt)
                #pragma unroll
                for (int rr = 0; rr < 4; ++rr) oacc[dt][rr] *= fo[rr];
        }
        float psum = 0.f;
        #pragma unroll
        for (int i = 0; i < 16; ++i) { xv[i] = exp2f(xv[i] - mrun); psum += xv[i]; }
        lrun += psum;

        #pragma unroll
        for (int st = 0; st < 4; ++st) {
            ushort4 w;
            w.x = f2bf(xv[st * 4 + 0]); w.y = f2bf(xv[st * 4 + 1]);
            w.z = f2bf(xv[st * 4 + 2]); w.w = f2bf(xv[st * 4 + 3]);
            const int slot8 = (st << 1) | (hi >> 1);
            *(ushort4*)&lds_p[wv][qr * 64 + ((slot8 ^ (qr & 7)) << 3) + ((hi & 1) << 2)] = w;
        }

        __builtin_amdgcn_s_setprio(1);
        #pragma unroll
        for (int ks = 0; ks < 2; ++ks) {
            if (!diag || wv >= 2 || ks == 0) {
                bf16x8 pa = *(const bf16x8*)&lds_p[wv][qr * 64 + ((((ks << 2) | hi) ^ (qr & 7)) << 3)];
                #pragma unroll
                for (int dt = 0; dt < 4; ++dt) {
                    const int dv = dt * 16 + qr;
                    bf16x8 vbf = *(const bf16x8*)&lds_vt[dv * VST + ((((ks << 2) + hi) ^ ((dv >> 3) & 7)) << 3)];
                    oacc[dt] = __builtin_amdgcn_mfma_f32_16x16x32_bf16(pa, vbf, oacc[dt], 0, 0, 0);
                }
            }
        }
        __builtin_amdgcn_s_setprio(0);

        if (j + 1 < nit) {
            __syncthreads();
            write_stage();
        }
    }

    {
        float lr = lrun;
        lr += __shfl_xor(lr, 16);
        lr += __shfl_xor(lr, 32);
        const float linv = 1.0f / lr;
        #pragma unroll
        for (int rr = 0; rr < 4; ++rr) {
            const float inv = __shfl(linv, hi * 4 + rr);
            float* go = out + bhbase + (size_t)(q0 + wv * 16 + hi * 4 + rr) * DDIM;
            #pragma unroll
            for (int dt = 0; dt < 4; ++dt)
                go[dt * 16 + qr] = oacc[dt][rr] * inv;
        }
    }
}

extern "C" void kernel_launch(void* const* d_in, const int* in_sizes, int n_in,
                              void* d_out, int out_size, void* d_ws, size_t ws_size,
                              hipStream_t stream) {
    (void)in_sizes; (void)n_in; (void)out_size;
    const float* q = (const float*)d_in[0];
    const float* k = (const float*)d_in[1];
    const float* v = (const float*)d_in[2];
    float* o = (float*)d_out;

    const size_t elems = (size_t)2 * NHEAD * TT * HD;
    const size_t need  = 2 * elems * sizeof(ushort);       // 16 MB
    if (ws_size >= need) {
        ushort* kbf = (ushort*)d_ws;
        ushort* vt  = kbf + elems;
        prepass_kernel<<<dim3(32, 32), 256, 0, stream>>>(k, v, kbf, vt);
        attn_main<<<dim3(1024), 256, 0, stream>>>(q, kbf, vt, o);
    } else {
        alibi_attn_fallback<<<dim3(1024), 256, 0, stream>>>(q, k, v, o);
    }
}